// Round 1
// baseline (3149.326 us; speedup 1.0000x reference)
//
#include <hip/hip_runtime.h>
#include <math.h>

#define S_LEN 4096
#define D_DIM 64
#define H_NUM 16
#define WIN   256
#define BAND  (2 * WIN + 1)   // 513

__global__ __launch_bounds__(256) void swa_kernel(
    const float* __restrict__ Q,
    const float* __restrict__ K,
    const float* __restrict__ V,
    float* __restrict__ out,
    float* __restrict__ attn)
{
    const int q   = blockIdx.x;
    const int h   = blockIdx.y;
    const int tid = threadIdx.x;

    const float* Kh = K + (size_t)h * S_LEN * D_DIM;
    const float* Vh = V + (size_t)h * S_LEN * D_DIM;

    __shared__ float qs[D_DIM];
    __shared__ float ps[BAND];
    __shared__ float red_m[4];
    __shared__ float red_s[4];
    __shared__ float oacc[4][D_DIM];

    // load query row (broadcast source)
    if (tid < D_DIM) {
        qs[tid] = Q[((size_t)h * S_LEN + q) * D_DIM + tid];
    }
    __syncthreads();

    const int k0 = max(q - WIN, 0);
    const int k1 = min(q + WIN, S_LEN - 1);
    const int nk = k1 - k0 + 1;

    // ---- scores: s = (q . k) / 8 ----
    float lmax = -1e30f;
    for (int i = tid; i < nk; i += 256) {
        const float4* Krow4 = (const float4*)(Kh + (size_t)(k0 + i) * D_DIM);
        float s = 0.f;
        #pragma unroll
        for (int d4 = 0; d4 < D_DIM / 4; ++d4) {
            float4 k4 = Krow4[d4];
            s += qs[d4 * 4 + 0] * k4.x;
            s += qs[d4 * 4 + 1] * k4.y;
            s += qs[d4 * 4 + 2] * k4.z;
            s += qs[d4 * 4 + 3] * k4.w;
        }
        s *= 0.125f;   // 1/sqrt(64)
        ps[i] = s;
        lmax = fmaxf(lmax, s);
    }

    // ---- block max ----
    #pragma unroll
    for (int off = 32; off; off >>= 1)
        lmax = fmaxf(lmax, __shfl_down(lmax, off, 64));
    if ((tid & 63) == 0) red_m[tid >> 6] = lmax;
    __syncthreads();
    const float m = fmaxf(fmaxf(red_m[0], red_m[1]), fmaxf(red_m[2], red_m[3]));

    // ---- exp + block sum ----
    float lsum = 0.f;
    for (int i = tid; i < nk; i += 256) {
        float e = __expf(ps[i] - m);
        ps[i] = e;
        lsum += e;
    }
    #pragma unroll
    for (int off = 32; off; off >>= 1)
        lsum += __shfl_down(lsum, off, 64);
    if ((tid & 63) == 0) red_s[tid >> 6] = lsum;
    __syncthreads();
    const float inv = 1.f / (red_s[0] + red_s[1] + red_s[2] + red_s[3]);

    // ---- normalize in LDS ----
    for (int i = tid; i < nk; i += 256)
        ps[i] *= inv;
    __syncthreads();

    // ---- write full attn row (zeros outside band), float4-coalesced ----
    float4* arow4 = (float4*)(attn + ((size_t)h * S_LEN + q) * S_LEN);
    for (int j4 = tid; j4 < S_LEN / 4; j4 += 256) {
        const int j = j4 * 4;
        float4 v4;
        v4.x = (j + 0 >= k0 && j + 0 <= k1) ? ps[j + 0 - k0] : 0.f;
        v4.y = (j + 1 >= k0 && j + 1 <= k1) ? ps[j + 1 - k0] : 0.f;
        v4.z = (j + 2 >= k0 && j + 2 <= k1) ? ps[j + 2 - k0] : 0.f;
        v4.w = (j + 3 >= k0 && j + 3 <= k1) ? ps[j + 3 - k0] : 0.f;
        arow4[j4] = v4;
    }

    // ---- PV: out[q,d] = sum_k p_k * V[k,d] ----
    const int g = tid >> 6;    // key-group 0..3
    const int d = tid & 63;    // dim
    float acc = 0.f;
    for (int i = g; i < nk; i += 4)
        acc += ps[i] * Vh[(size_t)(k0 + i) * D_DIM + d];
    oacc[g][d] = acc;
    __syncthreads();
    if (tid < D_DIM) {
        float o = oacc[0][tid] + oacc[1][tid] + oacc[2][tid] + oacc[3][tid];
        out[((size_t)h * S_LEN + q) * D_DIM + tid] = o;
    }
}

extern "C" void kernel_launch(void* const* d_in, const int* in_sizes, int n_in,
                              void* d_out, int out_size, void* d_ws, size_t ws_size,
                              hipStream_t stream) {
    const float* Q = (const float*)d_in[0];
    const float* K = (const float*)d_in[1];
    const float* V = (const float*)d_in[2];
    float* out  = (float*)d_out;
    float* attn = out + (size_t)H_NUM * S_LEN * D_DIM;

    dim3 grid(S_LEN, H_NUM);
    swa_kernel<<<grid, 256, 0, stream>>>(Q, K, V, out, attn);
}

// Round 3
// 1302.361 us; speedup vs baseline: 2.4182x; 2.4182x over previous
//
#include <hip/hip_runtime.h>
#include <math.h>

#define S_LEN 4096
#define D_DIM 64
#define H_NUM 16
#define WIN   256
#define TQ    16            // query rows per block
#define CK    64            // key rows per staged chunk
#define PSTR  528           // ps row stride (floats); nk <= 528 always

// LDS budget: ps 33792 + kv 16384 + qlds 4096 + linv 64 = 54336 B -> 3 blocks/CU
__global__ __launch_bounds__(256) void swa_kernel(
    const float* __restrict__ Q,
    const float* __restrict__ K,
    const float* __restrict__ V,
    float* __restrict__ out,
    float* __restrict__ attn)
{
    const int tid = threadIdx.x;
    const int q0  = blockIdx.x * TQ;
    const int h   = blockIdx.y;

    const float* __restrict__ Qh = Q + (size_t)h * S_LEN * D_DIM;
    const float* __restrict__ Kh = K + (size_t)h * S_LEN * D_DIM;
    const float* __restrict__ Vh = V + (size_t)h * S_LEN * D_DIM;

    __shared__ __align__(16) float ps[TQ * PSTR];
    __shared__ __align__(16) float kv[CK * D_DIM];     // XOR-swizzled float4 blocks
    __shared__ __align__(16) float qlds[TQ * D_DIM];
    __shared__ float linv[TQ];

    const int k0 = max(q0 - WIN, 0);
    const int k1 = min(q0 + TQ - 1 + WIN, S_LEN - 1);
    const int nk = k1 - k0 + 1;                 // always a multiple of 16
    const int nch = (nk + CK - 1) / CK;

    const int lane = tid & 63;
    const int qb   = (tid >> 6) * 4;            // wave-uniform: this wave's 4 q rows

    // stage Q tile once (reads are uniform broadcasts later; no swizzle needed)
    {
        const int qr = tid >> 4, b = tid & 15;
        *(float4*)(&qlds[qr * D_DIM + b * 4]) =
            *(const float4*)(Qh + (size_t)(q0 + qr) * D_DIM + b * 4);
    }

    // ---------------- Pass 1: scores into ps (band-masked per query row) ----------------
    for (int c = 0; c < nch; ++c) {
        const int kb = k0 + c * CK;
        #pragma unroll
        for (int i = 0; i < 4; ++i) {           // stage K chunk, coalesced
            const int idx = tid + 256 * i;      // 0..1023
            const int kr  = idx >> 4;           // row 0..63
            const int b   = idx & 15;           // float4 block 0..15
            const int kg  = min(kb + kr, S_LEN - 1);
            const float4 kd = *(const float4*)(Kh + (size_t)kg * D_DIM + b * 4);
            *(float4*)(&kv[kr * D_DIM + ((b ^ (kr & 15)) * 4)]) = kd;
        }
        __syncthreads();

        float a0 = 0.f, a1 = 0.f, a2 = 0.f, a3 = 0.f;
        #pragma unroll
        for (int d4 = 0; d4 < 16; ++d4) {
            const float4 kd = *(const float4*)(&kv[lane * D_DIM + ((d4 ^ (lane & 15)) * 4)]);
            const float4 x0 = *(const float4*)(&qlds[(qb + 0) * D_DIM + d4 * 4]);
            const float4 x1 = *(const float4*)(&qlds[(qb + 1) * D_DIM + d4 * 4]);
            const float4 x2 = *(const float4*)(&qlds[(qb + 2) * D_DIM + d4 * 4]);
            const float4 x3 = *(const float4*)(&qlds[(qb + 3) * D_DIM + d4 * 4]);
            a0 += x0.x * kd.x + x0.y * kd.y + x0.z * kd.z + x0.w * kd.w;
            a1 += x1.x * kd.x + x1.y * kd.y + x1.z * kd.z + x1.w * kd.w;
            a2 += x2.x * kd.x + x2.y * kd.y + x2.z * kd.z + x2.w * kd.w;
            a3 += x3.x * kd.x + x3.y * kd.y + x3.z * kd.z + x3.w * kd.w;
        }
        const int kk = c * CK + lane;
        if (kk < nk) {
            const int kglob = kb + lane;        // absolute key index
            const int qa    = q0 + qb;          // this wave's first query row
            // mask keys outside each row's own band: exp underflows to exactly 0,
            // matching the reference's exp(-1e9 - m) == 0 in fp32
            ps[(qb + 0) * PSTR + kk] =
                (kglob >= qa + 0 - WIN && kglob <= qa + 0 + WIN) ? a0 * 0.125f : -1e30f;
            ps[(qb + 1) * PSTR + kk] =
                (kglob >= qa + 1 - WIN && kglob <= qa + 1 + WIN) ? a1 * 0.125f : -1e30f;
            ps[(qb + 2) * PSTR + kk] =
                (kglob >= qa + 2 - WIN && kglob <= qa + 2 + WIN) ? a2 * 0.125f : -1e30f;
            ps[(qb + 3) * PSTR + kk] =
                (kglob >= qa + 3 - WIN && kglob <= qa + 3 + WIN) ? a3 * 0.125f : -1e30f;
        }
        __syncthreads();
    }

    // ---------------- softmax: per-q max, exp, sum ----------------
    {
        const int qg = tid >> 4, l16 = tid & 15;
        float* prow = &ps[qg * PSTR];
        float mx = -1e30f;
        for (int j = l16; j < nk; j += 16) mx = fmaxf(mx, prow[j]);
        #pragma unroll
        for (int off = 8; off; off >>= 1) mx = fmaxf(mx, __shfl_down(mx, off, 16));
        mx = __shfl(mx, 0, 16);
        float sm = 0.f;
        for (int j = l16; j < nk; j += 16) {
            const float e = __expf(prow[j] - mx);
            prow[j] = e;
            sm += e;
        }
        #pragma unroll
        for (int off = 8; off; off >>= 1) sm += __shfl_down(sm, off, 16);
        if (l16 == 0) linv[qg] = 1.f / sm;
    }
    __syncthreads();

    // ---------------- Pass 2: PV ----------------
    const int qv = tid >> 4;            // q row 0..15
    const int db = tid & 15;            // float4 block of d
    float4 o = make_float4(0.f, 0.f, 0.f, 0.f);
    for (int c = 0; c < nch; ++c) {
        const int kb = k0 + c * CK;
        #pragma unroll
        for (int i = 0; i < 4; ++i) {           // stage V chunk
            const int idx = tid + 256 * i;
            const int kr  = idx >> 4;
            const int b   = idx & 15;
            const int kg  = min(kb + kr, S_LEN - 1);
            const float4 vd = *(const float4*)(Vh + (size_t)kg * D_DIM + b * 4);
            *(float4*)(&kv[kr * D_DIM + ((b ^ (kr & 15)) * 4)]) = vd;
        }
        __syncthreads();
        const int kmax = min(CK, nk - c * CK);  // multiple of 16
        const float* prow = &ps[qv * PSTR + c * CK];
        for (int kk = 0; kk < kmax; kk += 4) {
            const float4 p4 = *(const float4*)(&prow[kk]);
            const float4 v0 = *(const float4*)(&kv[(kk + 0) * D_DIM + ((db ^ ((kk + 0) & 15)) * 4)]);
            const float4 v1 = *(const float4*)(&kv[(kk + 1) * D_DIM + ((db ^ ((kk + 1) & 15)) * 4)]);
            const float4 v2 = *(const float4*)(&kv[(kk + 2) * D_DIM + ((db ^ ((kk + 2) & 15)) * 4)]);
            const float4 v3 = *(const float4*)(&kv[(kk + 3) * D_DIM + ((db ^ ((kk + 3) & 15)) * 4)]);
            o.x += p4.x * v0.x + p4.y * v1.x + p4.z * v2.x + p4.w * v3.x;
            o.y += p4.x * v0.y + p4.y * v1.y + p4.z * v2.y + p4.w * v3.y;
            o.z += p4.x * v0.z + p4.y * v1.z + p4.z * v2.z + p4.w * v3.z;
            o.w += p4.x * v0.w + p4.y * v1.w + p4.z * v2.w + p4.w * v3.w;
        }
        __syncthreads();
    }
    {
        const float inv = linv[qv];
        o.x *= inv; o.y *= inv; o.z *= inv; o.w *= inv;
        *(float4*)(&out[((size_t)h * S_LEN + (q0 + qv)) * D_DIM + db * 4]) = o;
    }

    // ---------------- attn rows: zeros outside band, e*inv inside (LAST: no barrier after stores) ----------------
    for (int qq = 0; qq < TQ; ++qq) {
        const int qa  = q0 + qq;
        const int b0  = max(qa - WIN, 0);
        const int b1  = min(qa + WIN, S_LEN - 1);
        const float qi = linv[qq];
        const float* prow = &ps[qq * PSTR];
        float4* arow = (float4*)(attn + ((size_t)h * S_LEN + qa) * S_LEN);
        for (int j4 = tid; j4 < S_LEN / 4; j4 += 256) {
            const int j = j4 * 4;
            float4 w = make_float4(0.f, 0.f, 0.f, 0.f);
            if (j + 3 >= b0 && j <= b1) {
                if (j + 0 >= b0 && j + 0 <= b1) w.x = prow[j + 0 - k0] * qi;
                if (j + 1 >= b0 && j + 1 <= b1) w.y = prow[j + 1 - k0] * qi;
                if (j + 2 >= b0 && j + 2 <= b1) w.z = prow[j + 2 - k0] * qi;
                if (j + 3 >= b0 && j + 3 <= b1) w.w = prow[j + 3 - k0] * qi;
            }
            arow[j4] = w;
        }
    }
}

extern "C" void kernel_launch(void* const* d_in, const int* in_sizes, int n_in,
                              void* d_out, int out_size, void* d_ws, size_t ws_size,
                              hipStream_t stream) {
    const float* Q = (const float*)d_in[0];
    const float* K = (const float*)d_in[1];
    const float* V = (const float*)d_in[2];
    float* out  = (float*)d_out;
    float* attn = out + (size_t)H_NUM * S_LEN * D_DIM;

    dim3 grid(S_LEN / TQ, H_NUM);
    swa_kernel<<<grid, 256, 0, stream>>>(Q, K, V, out, attn);
}

// Round 4
// 1119.831 us; speedup vs baseline: 2.8123x; 1.1630x over previous
//
#include <hip/hip_runtime.h>
#include <math.h>

#define S_LEN 4096
#define D_DIM 64
#define H_NUM 16
#define WIN   256
#define TQ    16
#define NCH   9        // 9 chunks x 64 keys = 576 >= 513+15 band union
#define KSTR  72       // u16 stride of K-chunk / Q rows (pad breaks bank stride)
#define PBSTR 584      // u16 stride of pbf rows (576 keys + 8 pad, 16B-aligned)

typedef __attribute__((ext_vector_type(8))) short          bf16x8;
typedef __attribute__((ext_vector_type(4))) float          f32x4;
typedef __attribute__((ext_vector_type(8))) unsigned short u16x8;
typedef __attribute__((ext_vector_type(4))) unsigned short u16x4;

static __device__ __forceinline__ unsigned short f2bf(float x) {
    unsigned int u = __float_as_uint(x);
    u = (u + 0x7FFFu + ((u >> 16) & 1u)) >> 16;   // RNE
    return (unsigned short)u;
}
static __device__ __forceinline__ float bf2f(unsigned short h) {
    return __uint_as_float(((unsigned int)h) << 16);
}

// LDS: pbf 18688 + kvb 9216 + qbf 2304 + red 256 + linv 64 ~= 30.6 KB -> 5 blocks/CU
__global__ __launch_bounds__(256) void swa_kernel(
    const float* __restrict__ Q,
    const float* __restrict__ K,
    const float* __restrict__ V,
    float* __restrict__ out,
    float* __restrict__ attn)
{
    const int tid = threadIdx.x;
    const int q0  = blockIdx.x * TQ;
    const int h   = blockIdx.y;

    const float* __restrict__ Qh = Q + (size_t)h * S_LEN * D_DIM;
    const float* __restrict__ Kh = K + (size_t)h * S_LEN * D_DIM;
    const float* __restrict__ Vh = V + (size_t)h * S_LEN * D_DIM;

    __shared__ unsigned short qbf[TQ * KSTR];
    __shared__ unsigned short kvb[64 * KSTR];     // K chunk (stride 72) / Vt (stride 64)
    __shared__ unsigned short pbf[TQ * PBSTR];    // unnormalized exp(scores), bf16
    __shared__ float red[64];
    __shared__ float linv[TQ];

    const int k0   = max(q0 - WIN, 0);
    const int lane = tid & 63;
    const int wv   = tid >> 6;      // wave id: key-tile (pass1) / d-tile (PV)
    const int quad = lane >> 4;     // MFMA k-group / CD row-group
    const int n16  = lane & 15;     // MFMA m/n index

    // ---- stage Q tile as bf16 ----
    {
        const int row = tid >> 4, c4 = (tid & 15) * 4;
        const float4 v = *(const float4*)(Qh + (size_t)(q0 + row) * D_DIM + c4);
        u16x4 p; p.x = f2bf(v.x); p.y = f2bf(v.y); p.z = f2bf(v.z); p.w = f2bf(v.w);
        *(u16x4*)&qbf[row * KSTR + c4] = p;
    }
    __syncthreads();

    // Q A-fragments: A[m=n16][k=quad*8+j], k in [0,32) and [32,64)
    const bf16x8 aq0 = *(const bf16x8*)&qbf[n16 * KSTR + quad * 8];
    const bf16x8 aq1 = *(const bf16x8*)&qbf[n16 * KSTR + 32 + quad * 8];

    // ---------------- Pass 1: QK^T via MFMA, fused exp + pbf + row-sums ----------------
    float psum[4] = {0.f, 0.f, 0.f, 0.f};
    #pragma unroll
    for (int c = 0; c < NCH; ++c) {
        const int kb = k0 + c * 64;
        {   // stage K chunk -> bf16, row-major, stride 72
            const int key = tid >> 2, d0 = (tid & 3) * 16;
            const int kg  = min(kb + key, S_LEN - 1);
            const float4* s4 = (const float4*)(Kh + (size_t)kg * D_DIM + d0);
            const float4 x0 = s4[0], x1 = s4[1], x2 = s4[2], x3 = s4[3];
            u16x8 p0, p1;
            p0[0]=f2bf(x0.x); p0[1]=f2bf(x0.y); p0[2]=f2bf(x0.z); p0[3]=f2bf(x0.w);
            p0[4]=f2bf(x1.x); p0[5]=f2bf(x1.y); p0[6]=f2bf(x1.z); p0[7]=f2bf(x1.w);
            p1[0]=f2bf(x2.x); p1[1]=f2bf(x2.y); p1[2]=f2bf(x2.z); p1[3]=f2bf(x2.w);
            p1[4]=f2bf(x3.x); p1[5]=f2bf(x3.y); p1[6]=f2bf(x3.z); p1[7]=f2bf(x3.w);
            *(u16x8*)&kvb[key * KSTR + d0]     = p0;
            *(u16x8*)&kvb[key * KSTR + d0 + 8] = p1;
        }
        __syncthreads();

        // B[k=d][n=key]: lane reads K[key=wv*16+n16][d=quad*8+j] (contiguous)
        const bf16x8 b0 = *(const bf16x8*)&kvb[(wv * 16 + n16) * KSTR + quad * 8];
        const bf16x8 b1 = *(const bf16x8*)&kvb[(wv * 16 + n16) * KSTR + 32 + quad * 8];
        f32x4 acc = {0.f, 0.f, 0.f, 0.f};
        acc = __builtin_amdgcn_mfma_f32_16x16x32_bf16(aq0, b0, acc, 0, 0, 0);
        acc = __builtin_amdgcn_mfma_f32_16x16x32_bf16(aq1, b1, acc, 0, 0, 0);

        // D: col(lane&15)=key-in-tile, row=quad*4+reg=q row. No max-subtraction:
        // |scores| <~ 8 so exp() is safe in fp32 (ref's softmax shift cancels).
        const int key_abs = kb + wv * 16 + n16;
        #pragma unroll
        for (int r = 0; r < 4; ++r) {
            const int qrow  = quad * 4 + r;
            const int q_abs = q0 + qrow;
            const bool in   = (key_abs < S_LEN) &&
                              (key_abs >= q_abs - WIN) && (key_abs <= q_abs + WIN);
            const float e = in ? __expf(acc[r] * 0.125f) : 0.f;
            pbf[qrow * PBSTR + c * 64 + wv * 16 + n16] = f2bf(e);
            psum[r] += e;
        }
        __syncthreads();
    }

    // ---- row sums -> linv ----
    #pragma unroll
    for (int r = 0; r < 4; ++r) {
        float s = psum[r];
        s += __shfl_down(s, 8, 16);
        s += __shfl_down(s, 4, 16);
        s += __shfl_down(s, 2, 16);
        s += __shfl_down(s, 1, 16);
        if (n16 == 0) red[wv * 16 + quad * 4 + r] = s;
    }
    __syncthreads();
    if (tid < TQ)
        linv[tid] = 1.f / (red[tid] + red[16 + tid] + red[32 + tid] + red[48 + tid]);
    __syncthreads();

    // ---------------- Pass 2: PV via MFMA (V transposed + XOR-swizzled in LDS) ----------------
    f32x4 oacc = {0.f, 0.f, 0.f, 0.f};
    const int dd = wv * 16 + n16;                       // this lane's output d
    const int sd = ((dd >> 4) + (dd & 7)) & 7;          // read-side swizzle
    #pragma unroll
    for (int c = 0; c < NCH; ++c) {
        const int kb = k0 + c * 64;
        {   // stage V chunk transposed: Vt[d][key^8*s(d)] bf16, stride 64
            const int key = tid >> 2, d0 = (tid & 3) * 16;
            const int kg  = min(kb + key, S_LEN - 1);
            const float4* s4 = (const float4*)(Vh + (size_t)kg * D_DIM + d0);
            const float4 y0 = s4[0], y1 = s4[1], y2 = s4[2], y3 = s4[3];
            const float vals[16] = {y0.x,y0.y,y0.z,y0.w, y1.x,y1.y,y1.z,y1.w,
                                    y2.x,y2.y,y2.z,y2.w, y3.x,y3.y,y3.z,y3.w};
            #pragma unroll
            for (int jj = 0; jj < 16; ++jj) {
                const int d  = d0 + jj;
                const int sw = ((d >> 4) + (d & 7)) & 7;
                kvb[d * 64 + (key ^ (sw * 8))] = f2bf(vals[jj]);
            }
        }
        __syncthreads();

        // A = P[m=q][k=key] from pbf; B = Vt[k=key][n=d]
        const bf16x8 pa0 = *(const bf16x8*)&pbf[n16 * PBSTR + c * 64 + quad * 8];
        const bf16x8 pa1 = *(const bf16x8*)&pbf[n16 * PBSTR + c * 64 + 32 + quad * 8];
        const bf16x8 vb0 = *(const bf16x8*)&kvb[dd * 64 + 8 * (quad ^ sd)];
        const bf16x8 vb1 = *(const bf16x8*)&kvb[dd * 64 + 8 * ((4 + quad) ^ sd)];
        oacc = __builtin_amdgcn_mfma_f32_16x16x32_bf16(pa0, vb0, oacc, 0, 0, 0);
        oacc = __builtin_amdgcn_mfma_f32_16x16x32_bf16(pa1, vb1, oacc, 0, 0, 0);
        __syncthreads();
    }
    #pragma unroll
    for (int r = 0; r < 4; ++r) {
        const int qrow = quad * 4 + r;
        out[((size_t)h * S_LEN + q0 + qrow) * D_DIM + dd] = oacc[r] * linv[qrow];
    }

    // ---------------- attn rows: full 4096-wide, zeros outside band (LAST; nontemporal) ----------------
    for (int qq = 0; qq < TQ; ++qq) {
        const int qa  = q0 + qq;
        const int b0q = max(qa - WIN, 0);
        const int b1q = min(qa + WIN, S_LEN - 1);
        const float qi = linv[qq];
        f32x4* arow = (f32x4*)(attn + ((size_t)h * S_LEN + qa) * S_LEN);
        const unsigned short* prow = &pbf[qq * PBSTR];
        for (int j4 = tid; j4 < S_LEN / 4; j4 += 256) {
            const int j = j4 * 4;
            f32x4 w = {0.f, 0.f, 0.f, 0.f};
            if (j >= b0q && j + 3 <= b1q) {
                const u16x4 p = *(const u16x4*)&prow[j - k0];
                w[0] = bf2f(p.x) * qi; w[1] = bf2f(p.y) * qi;
                w[2] = bf2f(p.z) * qi; w[3] = bf2f(p.w) * qi;
            } else if (j + 3 >= b0q && j <= b1q) {
                #pragma unroll
                for (int e = 0; e < 4; ++e) {
                    const int jj = j + e;
                    if (jj >= b0q && jj <= b1q) w[e] = bf2f(prow[jj - k0]) * qi;
                }
            }
            __builtin_nontemporal_store(w, &arow[j4]);
        }
    }
}

extern "C" void kernel_launch(void* const* d_in, const int* in_sizes, int n_in,
                              void* d_out, int out_size, void* d_ws, size_t ws_size,
                              hipStream_t stream) {
    const float* Q = (const float*)d_in[0];
    const float* K = (const float*)d_in[1];
    const float* V = (const float*)d_in[2];
    float* out  = (float*)d_out;
    float* attn = out + (size_t)H_NUM * S_LEN * D_DIM;

    dim3 grid(S_LEN / TQ, H_NUM);
    swa_kernel<<<grid, 256, 0, stream>>>(Q, K, V, out, attn);
}